// Round 1
// baseline (659.941 us; speedup 1.0000x reference)
//
#include <hip/hip_runtime.h>

typedef __attribute__((ext_vector_type(4))) float f32x4;
typedef __attribute__((ext_vector_type(8))) short bf16x8;
typedef __attribute__((ext_vector_type(4))) unsigned short u16x4;

#define T_SEQ 2048
#define NH 16
#define HD 64

__device__ __forceinline__ unsigned short f2bf(float f) {
  unsigned int u = __builtin_bit_cast(unsigned int, f);
  return (unsigned short)((u + 0x7fffu + ((u >> 16) & 1u)) >> 16);
}

__device__ __forceinline__ void gload16(const void* g, void* l) {
  __builtin_amdgcn_global_load_lds(
      (const __attribute__((address_space(1))) unsigned int*)g,
      (__attribute__((address_space(3))) unsigned int*)l, 16, 0, 0);
}

// ---------------- convert f32 -> bf16 ----------------
__global__ void cvt_f32_bf16(const float* __restrict__ src,
                             unsigned short* __restrict__ dst, int n4) {
  int i = blockIdx.x * blockDim.x + threadIdx.x;
  if (i >= n4) return;
  f32x4 v = ((const f32x4*)src)[i];
  u16x4 r;
  r[0] = f2bf(v[0]); r[1] = f2bf(v[1]);
  r[2] = f2bf(v[2]); r[3] = f2bf(v[3]);
  ((u16x4*)dst)[i] = r;
}

// ---------------- GEMM core: 128x128 tile, A (MxK rm), B (NxK rm), K=1024 ----------------
__device__ __forceinline__ void gemm_core(const short* __restrict__ A,
                                          const short* __restrict__ Bm,
                                          int m0, int n0,
                                          short* la, short* lb,
                                          f32x4 acc[4][4]) {
  const int tid = threadIdx.x;
  const int lane = tid & 63;
  const int wid = tid >> 6;
  const int wr = wid >> 1, wc = wid & 1;
  const int lrow = lane & 15;
  const int lk = (lane >> 4) << 3;

#pragma unroll
  for (int m = 0; m < 4; ++m)
#pragma unroll
    for (int n = 0; n < 4; ++n)
      acc[m][n] = (f32x4){0.f, 0.f, 0.f, 0.f};

  for (int k0 = 0; k0 < 1024; k0 += 32) {
    __syncthreads();
#pragma unroll
    for (int i = 0; i < 2; ++i) {
      int f = i * 256 + tid;
      int row = f >> 2, c = (f & 3) << 3;
      gload16(A + (size_t)(m0 + row) * 1024 + k0 + c, la + f * 8);
      gload16(Bm + (size_t)(n0 + row) * 1024 + k0 + c, lb + f * 8);
    }
    __syncthreads();
    bf16x8 af[4], bf[4];
#pragma unroll
    for (int m = 0; m < 4; ++m)
      af[m] = *(const bf16x8*)(la + (wr * 64 + m * 16 + lrow) * 32 + lk);
#pragma unroll
    for (int n = 0; n < 4; ++n)
      bf[n] = *(const bf16x8*)(lb + (wc * 64 + n * 16 + lrow) * 32 + lk);
#pragma unroll
    for (int m = 0; m < 4; ++m)
#pragma unroll
      for (int n = 0; n < 4; ++n)
        acc[m][n] = __builtin_amdgcn_mfma_f32_16x16x32_bf16(af[m], bf[n],
                                                            acc[m][n], 0, 0, 0);
  }
}

// ---------------- fused QKV projection GEMM ----------------
// y=0: K (scale 1/32, (b,h,t,d)); y=1: Q (scale 1/256, (b,h,t,d)); y=2: V (scale 1/32, (b,h,d,t))
__global__ __launch_bounds__(256) void qkv_gemm(
    const short* __restrict__ xb, const short* __restrict__ wk,
    const short* __restrict__ wq, const short* __restrict__ wv,
    unsigned short* __restrict__ kdst, unsigned short* __restrict__ qdst,
    unsigned short* __restrict__ vdst) {
  __shared__ short la[128 * 32];
  __shared__ short lb[128 * 32];
  const int mb = blockIdx.x >> 3, nb = blockIdx.x & 7;
  const short* Bm;
  unsigned short* dst;
  float scale;
  int vmode;
  if (blockIdx.y == 0)      { Bm = wk; dst = kdst; scale = 0.03125f;    vmode = 0; }
  else if (blockIdx.y == 1) { Bm = wq; dst = qdst; scale = 0.00390625f; vmode = 0; }
  else                      { Bm = wv; dst = vdst; scale = 0.03125f;    vmode = 1; }

  f32x4 acc[4][4];
  gemm_core(xb, Bm, mb * 128, nb * 128, la, lb, acc);

  const int lane = threadIdx.x & 63, wid = threadIdx.x >> 6;
  const int wr = wid >> 1, wc = wid & 1;
#pragma unroll
  for (int m = 0; m < 4; ++m)
#pragma unroll
    for (int n = 0; n < 4; ++n)
#pragma unroll
      for (int r = 0; r < 4; ++r) {
        int gm = mb * 128 + wr * 64 + m * 16 + ((lane >> 4) << 2) + r;
        int gn = nb * 128 + wc * 64 + n * 16 + (lane & 15);
        int b = gm >> 11, t = gm & 2047;
        int h = gn >> 6, d = gn & 63;
        unsigned short val = f2bf(acc[m][n][r] * scale);
        if (vmode == 0)
          dst[(size_t)((b * NH + h) * T_SEQ + t) * HD + d] = val;
        else
          dst[(size_t)((b * NH + h) * HD + d) * T_SEQ + t] = val;
      }
}

// ---------------- flash attention ----------------
// grid: (B*NH)*32 blocks; block: 256 threads = 4 waves; wave handles 16 q rows.
// Q,K: (b,h,t,d) bf16 (scales folded). Vt: (b,h,d,t) bf16. O: (b,t,h*64+d) bf16.
__global__ __launch_bounds__(256) void attn_kernel(
    const short* __restrict__ Q, const short* __restrict__ Km,
    const short* __restrict__ Vt, unsigned short* __restrict__ O) {
  __shared__ short plds[4][16 * 32];
  const int tid = threadIdx.x, lane = tid & 63, wid = tid >> 6;
  const int qt = blockIdx.x & 31, bh = blockIdx.x >> 5;
  const int q0 = qt * 64 + wid * 16;
  const int lrow = lane & 15;
  const int lk = (lane >> 4) << 3;
  const size_t base = (size_t)bh * T_SEQ * HD;
  const short* Qp = Q + base;
  const short* Kp = Km + base;
  const short* Vp = Vt + base;

  bf16x8 qf0 = *(const bf16x8*)(Qp + (size_t)(q0 + lrow) * HD + lk);
  bf16x8 qf1 = *(const bf16x8*)(Qp + (size_t)(q0 + lrow) * HD + 32 + lk);

  f32x4 o0 = {0.f, 0.f, 0.f, 0.f}, o1 = o0, o2 = o0, o3 = o0;
  float m_r[4] = {-1e30f, -1e30f, -1e30f, -1e30f};
  float l_r[4] = {0.f, 0.f, 0.f, 0.f};
  short* myp = &plds[wid][0];

  const int kend = q0 + 16;
  for (int ks = 0; ks < kend; ks += 32) {
    f32x4 s0 = {0.f, 0.f, 0.f, 0.f}, s1 = s0;
    bf16x8 kf;
    kf = *(const bf16x8*)(Kp + (size_t)(ks + lrow) * HD + lk);
    s0 = __builtin_amdgcn_mfma_f32_16x16x32_bf16(qf0, kf, s0, 0, 0, 0);
    kf = *(const bf16x8*)(Kp + (size_t)(ks + lrow) * HD + 32 + lk);
    s0 = __builtin_amdgcn_mfma_f32_16x16x32_bf16(qf1, kf, s0, 0, 0, 0);
    kf = *(const bf16x8*)(Kp + (size_t)(ks + 16 + lrow) * HD + lk);
    s1 = __builtin_amdgcn_mfma_f32_16x16x32_bf16(qf0, kf, s1, 0, 0, 0);
    kf = *(const bf16x8*)(Kp + (size_t)(ks + 16 + lrow) * HD + 32 + lk);
    s1 = __builtin_amdgcn_mfma_f32_16x16x32_bf16(qf1, kf, s1, 0, 0, 0);

    if (ks + 31 > q0) {  // causal mask needed on this tile
      int kc = ks + (lane & 15);
      int qg = q0 + ((lane >> 4) << 2);
#pragma unroll
      for (int r = 0; r < 4; ++r) {
        if (kc > qg + r) s0[r] = -1e30f;
        if (kc + 16 > qg + r) s1[r] = -1e30f;
      }
    }

    float p0[4], p1[4], resc[4];
#pragma unroll
    for (int r = 0; r < 4; ++r) {
      float mx = fmaxf(s0[r], s1[r]);
      mx = fmaxf(mx, __shfl_xor(mx, 1));
      mx = fmaxf(mx, __shfl_xor(mx, 2));
      mx = fmaxf(mx, __shfl_xor(mx, 4));
      mx = fmaxf(mx, __shfl_xor(mx, 8));
      float mn = fmaxf(m_r[r], mx);
      float e0 = __expf(s0[r] - mn), e1 = __expf(s1[r] - mn);
      float rsc = __expf(m_r[r] - mn);
      m_r[r] = mn;
      float rsum = e0 + e1;
      rsum += __shfl_xor(rsum, 1);
      rsum += __shfl_xor(rsum, 2);
      rsum += __shfl_xor(rsum, 4);
      rsum += __shfl_xor(rsum, 8);
      l_r[r] = l_r[r] * rsc + rsum;
      resc[r] = rsc;
      p0[r] = e0; p1[r] = e1;
    }
#pragma unroll
    for (int r = 0; r < 4; ++r) {
      o0[r] *= resc[r]; o1[r] *= resc[r];
      o2[r] *= resc[r]; o3[r] *= resc[r];
    }
    // P (16x32) -> LDS as bf16, D-layout write, A-layout read
#pragma unroll
    for (int r = 0; r < 4; ++r) {
      int row = ((lane >> 4) << 2) + r;
      myp[row * 32 + (lane & 15)] = (short)f2bf(p0[r]);
      myp[row * 32 + 16 + (lane & 15)] = (short)f2bf(p1[r]);
    }
    bf16x8 pa = *(const bf16x8*)(myp + lrow * 32 + lk);
    bf16x8 vf;
    vf = *(const bf16x8*)(Vp + (size_t)(0 + lrow) * T_SEQ + ks + lk);
    o0 = __builtin_amdgcn_mfma_f32_16x16x32_bf16(pa, vf, o0, 0, 0, 0);
    vf = *(const bf16x8*)(Vp + (size_t)(16 + lrow) * T_SEQ + ks + lk);
    o1 = __builtin_amdgcn_mfma_f32_16x16x32_bf16(pa, vf, o1, 0, 0, 0);
    vf = *(const bf16x8*)(Vp + (size_t)(32 + lrow) * T_SEQ + ks + lk);
    o2 = __builtin_amdgcn_mfma_f32_16x16x32_bf16(pa, vf, o2, 0, 0, 0);
    vf = *(const bf16x8*)(Vp + (size_t)(48 + lrow) * T_SEQ + ks + lk);
    o3 = __builtin_amdgcn_mfma_f32_16x16x32_bf16(pa, vf, o3, 0, 0, 0);
  }

#pragma unroll
  for (int r = 0; r < 4; ++r) {
    float inv = 1.0f / l_r[r];
    o0[r] *= inv; o1[r] *= inv; o2[r] *= inv; o3[r] *= inv;
  }
  const int b = bh >> 4, h = bh & 15;
#pragma unroll
  for (int r = 0; r < 4; ++r) {
    int t = q0 + ((lane >> 4) << 2) + r;
    unsigned short* dst = O + (size_t)(b * T_SEQ + t) * 1024 + h * 64 + (lane & 15);
    dst[0]  = f2bf(o0[r]);
    dst[16] = f2bf(o1[r]);
    dst[32] = f2bf(o2[r]);
    dst[48] = f2bf(o3[r]);
  }
}

// ---------------- output projection GEMM (writes f32) ----------------
__global__ __launch_bounds__(256) void proj_gemm(const short* __restrict__ ain,
                                                 const short* __restrict__ wp,
                                                 float* __restrict__ out) {
  __shared__ short la[128 * 32];
  __shared__ short lb[128 * 32];
  const int mb = blockIdx.x >> 3, nb = blockIdx.x & 7;
  f32x4 acc[4][4];
  gemm_core(ain, wp, mb * 128, nb * 128, la, lb, acc);
  const int lane = threadIdx.x & 63, wid = threadIdx.x >> 6;
  const int wr = wid >> 1, wc = wid & 1;
#pragma unroll
  for (int m = 0; m < 4; ++m)
#pragma unroll
    for (int n = 0; n < 4; ++n)
#pragma unroll
      for (int r = 0; r < 4; ++r) {
        int gm = mb * 128 + wr * 64 + m * 16 + ((lane >> 4) << 2) + r;
        int gn = nb * 128 + wc * 64 + n * 16 + (lane & 15);
        out[(size_t)gm * 1024 + gn] = acc[m][n][r] * 0.03125f;
      }
}

extern "C" void kernel_launch(void* const* d_in, const int* in_sizes, int n_in,
                              void* d_out, int out_size, void* d_ws, size_t ws_size,
                              hipStream_t stream) {
  const float* x  = (const float*)d_in[0];
  const float* Wk = (const float*)d_in[1];
  const float* Wq = (const float*)d_in[2];
  const float* Wv = (const float*)d_in[3];
  const float* Wp = (const float*)d_in[4];
  float* out = (float*)d_out;
  char* ws = (char*)d_ws;
  const size_t MB = 1024ull * 1024ull;

  unsigned short* q_ws = (unsigned short*)(ws + 0 * MB);
  unsigned short* k_ws = (unsigned short*)(ws + 16 * MB);
  unsigned short* v_ws = (unsigned short*)(ws + 32 * MB);   // transposed (b,h,d,t)
  unsigned short* xa   = (unsigned short*)(ws + 48 * MB);   // x bf16, later attn-out
  unsigned short* wkb  = (unsigned short*)(ws + 64 * MB);
  unsigned short* wqb  = wkb + 1048576;
  unsigned short* wvb  = wqb + 1048576;
  unsigned short* wpb  = wvb + 1048576;

  cvt_f32_bf16<<<8192, 256, 0, stream>>>(x, xa, 2097152);
  cvt_f32_bf16<<<1024, 256, 0, stream>>>(Wk, wkb, 262144);
  cvt_f32_bf16<<<1024, 256, 0, stream>>>(Wq, wqb, 262144);
  cvt_f32_bf16<<<1024, 256, 0, stream>>>(Wv, wvb, 262144);
  cvt_f32_bf16<<<1024, 256, 0, stream>>>(Wp, wpb, 262144);

  qkv_gemm<<<dim3(512, 3), 256, 0, stream>>>(
      (const short*)xa, (const short*)wkb, (const short*)wqb, (const short*)wvb,
      k_ws, q_ws, v_ws);

  attn_kernel<<<2048, 256, 0, stream>>>(
      (const short*)q_ws, (const short*)k_ws, (const short*)v_ws, xa);

  proj_gemm<<<512, 256, 0, stream>>>((const short*)xa, (const short*)wpb, out);
}

// Round 2
// 345.909 us; speedup vs baseline: 1.9078x; 1.9078x over previous
//
#include <hip/hip_runtime.h>

typedef __attribute__((ext_vector_type(4))) float f32x4;
typedef __attribute__((ext_vector_type(16))) float f32x16;
typedef __attribute__((ext_vector_type(8))) short bf16x8;
typedef __attribute__((ext_vector_type(4))) unsigned short u16x4;
typedef __attribute__((ext_vector_type(4))) unsigned int u32x4;

#define T_SEQ 2048
#define NH 16
#define HD 64

__device__ __forceinline__ unsigned short f2bf(float f) {
  unsigned int u = __builtin_bit_cast(unsigned int, f);
  return (unsigned short)((u + 0x7fffu + ((u >> 16) & 1u)) >> 16);
}

__device__ __forceinline__ unsigned int cvtpk(float a, float b) {
  unsigned int r;
  asm("v_cvt_pk_bf16_f32 %0, %1, %2" : "=v"(r) : "v"(a), "v"(b));
  return r;
}

__device__ __forceinline__ bf16x8 mk8(unsigned int w0, unsigned int w1,
                                      unsigned int w2, unsigned int w3) {
  u32x4 t = {w0, w1, w2, w3};
  return __builtin_bit_cast(bf16x8, t);
}

__device__ __forceinline__ void gload16(const void* g, void* l) {
  __builtin_amdgcn_global_load_lds(
      (const __attribute__((address_space(1))) unsigned int*)g,
      (__attribute__((address_space(3))) unsigned int*)l, 16, 0, 0);
}

#define MFMA32(a, b, c) __builtin_amdgcn_mfma_f32_32x32x16_bf16(a, b, c, 0, 0, 0)

// ---------------- convert f32 -> bf16 ----------------
__global__ void cvt_f32_bf16(const float* __restrict__ src,
                             unsigned short* __restrict__ dst, int n4) {
  int i = blockIdx.x * blockDim.x + threadIdx.x;
  if (i >= n4) return;
  f32x4 v = ((const f32x4*)src)[i];
  u16x4 r;
  r[0] = f2bf(v[0]); r[1] = f2bf(v[1]);
  r[2] = f2bf(v[2]); r[3] = f2bf(v[3]);
  ((u16x4*)dst)[i] = r;
}

// ---------------- GEMM core: 128x128 tile, A (MxK rm), B (NxK rm), K=1024 ----------------
__device__ __forceinline__ void gemm_core(const short* __restrict__ A,
                                          const short* __restrict__ Bm,
                                          int m0, int n0,
                                          short* la, short* lb,
                                          f32x4 acc[4][4]) {
  const int tid = threadIdx.x;
  const int lane = tid & 63;
  const int wid = tid >> 6;
  const int wr = wid >> 1, wc = wid & 1;
  const int lrow = lane & 15;
  const int lk = (lane >> 4) << 3;

#pragma unroll
  for (int m = 0; m < 4; ++m)
#pragma unroll
    for (int n = 0; n < 4; ++n)
      acc[m][n] = (f32x4){0.f, 0.f, 0.f, 0.f};

  for (int k0 = 0; k0 < 1024; k0 += 32) {
    __syncthreads();
#pragma unroll
    for (int i = 0; i < 2; ++i) {
      int f = i * 256 + tid;
      int row = f >> 2, c = (f & 3) << 3;
      gload16(A + (size_t)(m0 + row) * 1024 + k0 + c, la + f * 8);
      gload16(Bm + (size_t)(n0 + row) * 1024 + k0 + c, lb + f * 8);
    }
    __syncthreads();
    bf16x8 af[4], bfr[4];
#pragma unroll
    for (int m = 0; m < 4; ++m)
      af[m] = *(const bf16x8*)(la + (wr * 64 + m * 16 + lrow) * 32 + lk);
#pragma unroll
    for (int n = 0; n < 4; ++n)
      bfr[n] = *(const bf16x8*)(lb + (wc * 64 + n * 16 + lrow) * 32 + lk);
#pragma unroll
    for (int m = 0; m < 4; ++m)
#pragma unroll
      for (int n = 0; n < 4; ++n)
        acc[m][n] = __builtin_amdgcn_mfma_f32_16x16x32_bf16(af[m], bfr[n],
                                                            acc[m][n], 0, 0, 0);
  }
}

// ---------------- fused QKV projection GEMM ----------------
// y=0: K (scale 1/32, (b,h,t,d)); y=1: Q (scale log2e/256, (b,h,t,d)); y=2: V (scale 1/32, (b,h,d,t))
__global__ __launch_bounds__(256) void qkv_gemm(
    const short* __restrict__ xb, const short* __restrict__ wk,
    const short* __restrict__ wq, const short* __restrict__ wv,
    unsigned short* __restrict__ kdst, unsigned short* __restrict__ qdst,
    unsigned short* __restrict__ vdst) {
  __shared__ short la[128 * 32];
  __shared__ short lb[128 * 32];
  const int mb = blockIdx.x >> 3, nb = blockIdx.x & 7;
  const short* Bm;
  unsigned short* dst;
  float scale;
  int vmode;
  if (blockIdx.y == 0)      { Bm = wk; dst = kdst; scale = 0.03125f;    vmode = 0; }
  else if (blockIdx.y == 1) { Bm = wq; dst = qdst; scale = 0.00390625f * 1.44269504088896340736f; vmode = 0; }
  else                      { Bm = wv; dst = vdst; scale = 0.03125f;    vmode = 1; }

  f32x4 acc[4][4];
  gemm_core(xb, Bm, mb * 128, nb * 128, la, lb, acc);

  const int lane = threadIdx.x & 63, wid = threadIdx.x >> 6;
  const int wr = wid >> 1, wc = wid & 1;
#pragma unroll
  for (int m = 0; m < 4; ++m)
#pragma unroll
    for (int n = 0; n < 4; ++n)
#pragma unroll
      for (int r = 0; r < 4; ++r) {
        int gm = mb * 128 + wr * 64 + m * 16 + ((lane >> 4) << 2) + r;
        int gn = nb * 128 + wc * 64 + n * 16 + (lane & 15);
        int b = gm >> 11, t = gm & 2047;
        int h = gn >> 6, d = gn & 63;
        unsigned short val = f2bf(acc[m][n][r] * scale);
        if (vmode == 0)
          dst[(size_t)((b * NH + h) * T_SEQ + t) * HD + d] = val;
        else
          dst[(size_t)((b * NH + h) * HD + d) * T_SEQ + t] = val;
      }
}

// ---------------- flash attention v2: swapped QK^T, in-register softmax ----------------
// grid: 1024 blocks = 16 qblocks (reversed) x 64 bh; block: 256 = 4 waves.
// Each wave: 32 q rows, k-tiles of 64, 32x32x16 MFMA, no LDS, no barriers.
// Q pre-scaled by C^-.5*hd^-.5*log2e; K by C^-.5; V by C^-.5. Vt is (b,h,d,t).
__global__ __launch_bounds__(256) void attn_kernel(
    const short* __restrict__ Q, const short* __restrict__ Km,
    const short* __restrict__ Vt, unsigned short* __restrict__ O) {
  const int tid = threadIdx.x, lane = tid & 63, wid = tid >> 6;
  const int bid = blockIdx.x;
  const int qt = 15 - (bid >> 6);   // heaviest q-blocks dispatch first
  const int bh = bid & 63;
  const int q0w = qt * 128 + wid * 32;
  const int hi = lane >> 5;
  const int l31 = lane & 31;

  const size_t base = (size_t)bh * T_SEQ * HD;
  const short* Qp = Q + base;
  const short* Kp = Km + base;
  const short* Vp = Vt + base;   // (d, t) rows of length 2048

  // Q fragments (B-operand): col=q=l31, elem j -> d = s*16 + hi*8 + j
  bf16x8 qf[4];
#pragma unroll
  for (int s = 0; s < 4; ++s)
    qf[s] = *(const bf16x8*)(Qp + (size_t)(q0w + l31) * HD + s * 16 + hi * 8);

  f32x16 oa = {0.f}, ob = {0.f};
#pragma unroll
  for (int r = 0; r < 16; ++r) { oa[r] = 0.f; ob[r] = 0.f; }
  float m_r = -1e30f, l_r = 0.f;

  const int ntiles = (q0w + 32 + 63) >> 6;
  for (int it = 0; it < ntiles; ++it) {
    const int kb = it * 64;
    // ---- QK^T (S^T tiles: k rows x q cols) ----
    f32x16 s0, s1;
#pragma unroll
    for (int r = 0; r < 16; ++r) { s0[r] = 0.f; s1[r] = 0.f; }
    const short* Kb = Kp + (size_t)(kb + l31) * HD + hi * 8;
    bf16x8 kf0[4], kf1[4];
#pragma unroll
    for (int s = 0; s < 4; ++s) {
      kf0[s] = *(const bf16x8*)(Kb + s * 16);
      kf1[s] = *(const bf16x8*)(Kb + 32 * HD + s * 16);
    }
#pragma unroll
    for (int s = 0; s < 4; ++s) {
      s0 = MFMA32(kf0[s], qf[s], s0);
      s1 = MFMA32(kf1[s], qf[s], s1);
    }

    // ---- causal mask (boundary tiles only) ----
    if (kb + 63 > q0w) {
      const int q = q0w + l31;
#pragma unroll
      for (int r = 0; r < 16; ++r) {
        int k0 = kb + (r & 3) + 8 * (r >> 2) + 4 * hi;
        if (k0 > q) s0[r] = -1e30f;
        if (k0 + 32 > q) s1[r] = -1e30f;
      }
    }

    // ---- online softmax (per-q: in-register + one shfl_xor(32)) ----
    float mx = -1e30f;
#pragma unroll
    for (int r = 0; r < 16; ++r) mx = fmaxf(mx, fmaxf(s0[r], s1[r]));
    mx = fmaxf(mx, __shfl_xor(mx, 32));
    const float mn = fmaxf(m_r, mx);
    const float rsc = exp2f(m_r - mn);
    m_r = mn;
    float rs = 0.f;
#pragma unroll
    for (int r = 0; r < 16; ++r) {
      s0[r] = exp2f(s0[r] - mn); rs += s0[r];
      s1[r] = exp2f(s1[r] - mn); rs += s1[r];
    }
    rs += __shfl_xor(rs, 32);
    l_r = l_r * rsc + rs;
#pragma unroll
    for (int r = 0; r < 16; ++r) { oa[r] *= rsc; ob[r] *= rsc; }

    // ---- pack P -> B-fragments (cvt_pk + shfl_xor(32) + select) ----
    bf16x8 pf[4];
    {
      unsigned int t0 = cvtpk(s0[0], s0[1]),  t1 = cvtpk(s0[2], s0[3]);
      unsigned int t2 = cvtpk(s0[4], s0[5]),  t3 = cvtpk(s0[6], s0[7]);
      unsigned int t4 = cvtpk(s0[8], s0[9]),  t5 = cvtpk(s0[10], s0[11]);
      unsigned int t6 = cvtpk(s0[12], s0[13]), t7 = cvtpk(s0[14], s0[15]);
      unsigned int o0 = __shfl_xor((int)t0, 32), o1 = __shfl_xor((int)t1, 32);
      unsigned int o2 = __shfl_xor((int)t2, 32), o3 = __shfl_xor((int)t3, 32);
      unsigned int o4 = __shfl_xor((int)t4, 32), o5 = __shfl_xor((int)t5, 32);
      unsigned int o6 = __shfl_xor((int)t6, 32), o7 = __shfl_xor((int)t7, 32);
      pf[0] = mk8(hi ? o2 : t0, hi ? o3 : t1, hi ? t2 : o0, hi ? t3 : o1);
      pf[1] = mk8(hi ? o6 : t4, hi ? o7 : t5, hi ? t6 : o4, hi ? t7 : o5);
    }
    {
      unsigned int t0 = cvtpk(s1[0], s1[1]),  t1 = cvtpk(s1[2], s1[3]);
      unsigned int t2 = cvtpk(s1[4], s1[5]),  t3 = cvtpk(s1[6], s1[7]);
      unsigned int t4 = cvtpk(s1[8], s1[9]),  t5 = cvtpk(s1[10], s1[11]);
      unsigned int t6 = cvtpk(s1[12], s1[13]), t7 = cvtpk(s1[14], s1[15]);
      unsigned int o0 = __shfl_xor((int)t0, 32), o1 = __shfl_xor((int)t1, 32);
      unsigned int o2 = __shfl_xor((int)t2, 32), o3 = __shfl_xor((int)t3, 32);
      unsigned int o4 = __shfl_xor((int)t4, 32), o5 = __shfl_xor((int)t5, 32);
      unsigned int o6 = __shfl_xor((int)t6, 32), o7 = __shfl_xor((int)t7, 32);
      pf[2] = mk8(hi ? o2 : t0, hi ? o3 : t1, hi ? t2 : o0, hi ? t3 : o1);
      pf[3] = mk8(hi ? o6 : t4, hi ? o7 : t5, hi ? t6 : o4, hi ? t7 : o5);
    }

    // ---- PV: O^T += V^T * P^T ----
    const short* Vb = Vp + (size_t)l31 * T_SEQ + kb + hi * 8;
#pragma unroll
    for (int ks = 0; ks < 4; ++ks) {
      bf16x8 vf0 = *(const bf16x8*)(Vb + ks * 16);
      bf16x8 vf1 = *(const bf16x8*)(Vb + 32 * T_SEQ + ks * 16);
      oa = MFMA32(vf0, pf[ks], oa);
      ob = MFMA32(vf1, pf[ks], ob);
    }
  }

  // ---- normalize + write O (b, t, h*64+d) ----
  const float linv = 1.0f / l_r;
  const int b = bh >> 4, h = bh & 15;
  const int t = q0w + l31;
  unsigned short* Orow = O + (size_t)(b * T_SEQ + t) * 1024 + h * HD;
#pragma unroll
  for (int r = 0; r < 16; r += 2) {
    int d = (r & 3) + 8 * (r >> 2) + 4 * hi;
    *(unsigned int*)(Orow + d)      = cvtpk(oa[r] * linv, oa[r + 1] * linv);
    *(unsigned int*)(Orow + 32 + d) = cvtpk(ob[r] * linv, ob[r + 1] * linv);
  }
}

// ---------------- output projection GEMM (writes f32) ----------------
__global__ __launch_bounds__(256) void proj_gemm(const short* __restrict__ ain,
                                                 const short* __restrict__ wp,
                                                 float* __restrict__ out) {
  __shared__ short la[128 * 32];
  __shared__ short lb[128 * 32];
  const int mb = blockIdx.x >> 3, nb = blockIdx.x & 7;
  f32x4 acc[4][4];
  gemm_core(ain, wp, mb * 128, nb * 128, la, lb, acc);
  const int lane = threadIdx.x & 63, wid = threadIdx.x >> 6;
  const int wr = wid >> 1, wc = wid & 1;
#pragma unroll
  for (int m = 0; m < 4; ++m)
#pragma unroll
    for (int n = 0; n < 4; ++n)
#pragma unroll
      for (int r = 0; r < 4; ++r) {
        int gm = mb * 128 + wr * 64 + m * 16 + ((lane >> 4) << 2) + r;
        int gn = nb * 128 + wc * 64 + n * 16 + (lane & 15);
        out[(size_t)gm * 1024 + gn] = acc[m][n][r] * 0.03125f;
      }
}

extern "C" void kernel_launch(void* const* d_in, const int* in_sizes, int n_in,
                              void* d_out, int out_size, void* d_ws, size_t ws_size,
                              hipStream_t stream) {
  const float* x  = (const float*)d_in[0];
  const float* Wk = (const float*)d_in[1];
  const float* Wq = (const float*)d_in[2];
  const float* Wv = (const float*)d_in[3];
  const float* Wp = (const float*)d_in[4];
  float* out = (float*)d_out;
  char* ws = (char*)d_ws;
  const size_t MB = 1024ull * 1024ull;

  unsigned short* q_ws = (unsigned short*)(ws + 0 * MB);
  unsigned short* k_ws = (unsigned short*)(ws + 16 * MB);
  unsigned short* v_ws = (unsigned short*)(ws + 32 * MB);   // transposed (b,h,d,t)
  unsigned short* xa   = (unsigned short*)(ws + 48 * MB);   // x bf16, later attn-out
  unsigned short* wkb  = (unsigned short*)(ws + 64 * MB);
  unsigned short* wqb  = wkb + 1048576;
  unsigned short* wvb  = wqb + 1048576;
  unsigned short* wpb  = wvb + 1048576;

  cvt_f32_bf16<<<8192, 256, 0, stream>>>(x, xa, 2097152);
  cvt_f32_bf16<<<1024, 256, 0, stream>>>(Wk, wkb, 262144);
  cvt_f32_bf16<<<1024, 256, 0, stream>>>(Wq, wqb, 262144);
  cvt_f32_bf16<<<1024, 256, 0, stream>>>(Wv, wvb, 262144);
  cvt_f32_bf16<<<1024, 256, 0, stream>>>(Wp, wpb, 262144);

  qkv_gemm<<<dim3(512, 3), 256, 0, stream>>>(
      (const short*)xa, (const short*)wkb, (const short*)wqb, (const short*)wvb,
      k_ws, q_ws, v_ws);

  attn_kernel<<<1024, 256, 0, stream>>>(
      (const short*)q_ws, (const short*)k_ws, (const short*)v_ws, xa);

  proj_gemm<<<512, 256, 0, stream>>>((const short*)xa, (const short*)wpb, out);
}

// Round 3
// 315.267 us; speedup vs baseline: 2.0933x; 1.0972x over previous
//
#include <hip/hip_runtime.h>

typedef __attribute__((ext_vector_type(4))) float f32x4;
typedef __attribute__((ext_vector_type(16))) float f32x16;
typedef __attribute__((ext_vector_type(8))) short bf16x8;
typedef __attribute__((ext_vector_type(4))) unsigned short u16x4;
typedef __attribute__((ext_vector_type(4))) unsigned int u32x4;

#define T_SEQ 2048
#define NH 16
#define HD 64

__device__ __forceinline__ unsigned short f2bf(float f) {
  unsigned int u = __builtin_bit_cast(unsigned int, f);
  return (unsigned short)((u + 0x7fffu + ((u >> 16) & 1u)) >> 16);
}

__device__ __forceinline__ unsigned int cvtpk(float a, float b) {
  unsigned int r;
  asm("v_cvt_pk_bf16_f32 %0, %1, %2" : "=v"(r) : "v"(a), "v"(b));
  return r;
}

__device__ __forceinline__ bf16x8 mk8(unsigned int w0, unsigned int w1,
                                      unsigned int w2, unsigned int w3) {
  u32x4 t = {w0, w1, w2, w3};
  return __builtin_bit_cast(bf16x8, t);
}

__device__ __forceinline__ void gload16(const void* g, void* l) {
  __builtin_amdgcn_global_load_lds(
      (const __attribute__((address_space(1))) unsigned int*)g,
      (__attribute__((address_space(3))) unsigned int*)l, 16, 0, 0);
}

#define MFMA32(a, b, c) __builtin_amdgcn_mfma_f32_32x32x16_bf16(a, b, c, 0, 0, 0)

// ---------------- convert f32 -> bf16 ----------------
__global__ void cvt_f32_bf16(const float* __restrict__ src,
                             unsigned short* __restrict__ dst, int n4) {
  int i = blockIdx.x * blockDim.x + threadIdx.x;
  if (i >= n4) return;
  f32x4 v = ((const f32x4*)src)[i];
  u16x4 r;
  r[0] = f2bf(v[0]); r[1] = f2bf(v[1]);
  r[2] = f2bf(v[2]); r[3] = f2bf(v[3]);
  ((u16x4*)dst)[i] = r;
}

// four 1024x1024 weight converts in one launch (1024 blocks each)
__global__ void cvt4_w(const float* __restrict__ s0, const float* __restrict__ s1,
                       const float* __restrict__ s2, const float* __restrict__ s3,
                       unsigned short* d0, unsigned short* d1,
                       unsigned short* d2, unsigned short* d3) {
  int bid = blockIdx.x;
  int which = bid >> 10;
  const float* s = which == 0 ? s0 : which == 1 ? s1 : which == 2 ? s2 : s3;
  unsigned short* d = which == 0 ? d0 : which == 1 ? d1 : which == 2 ? d2 : d3;
  int i = (bid & 1023) * 256 + threadIdx.x;
  f32x4 v = ((const f32x4*)s)[i];
  u16x4 r;
  r[0] = f2bf(v[0]); r[1] = f2bf(v[1]);
  r[2] = f2bf(v[2]); r[3] = f2bf(v[3]);
  ((u16x4*)d)[i] = r;
}

// ---------------- GEMM core: 128x128 tile, A (MxK rm), B (NxK rm), K=1024 ----------------
__device__ __forceinline__ void gemm_core(const short* __restrict__ A,
                                          const short* __restrict__ Bm,
                                          int m0, int n0,
                                          short* la, short* lb,
                                          f32x4 acc[4][4]) {
  const int tid = threadIdx.x;
  const int lane = tid & 63;
  const int wid = tid >> 6;
  const int wr = wid >> 1, wc = wid & 1;
  const int lrow = lane & 15;
  const int lk = (lane >> 4) << 3;

#pragma unroll
  for (int m = 0; m < 4; ++m)
#pragma unroll
    for (int n = 0; n < 4; ++n)
      acc[m][n] = (f32x4){0.f, 0.f, 0.f, 0.f};

  for (int k0 = 0; k0 < 1024; k0 += 32) {
    __syncthreads();
#pragma unroll
    for (int i = 0; i < 2; ++i) {
      int f = i * 256 + tid;
      int row = f >> 2, c = (f & 3) << 3;
      gload16(A + (size_t)(m0 + row) * 1024 + k0 + c, la + f * 8);
      gload16(Bm + (size_t)(n0 + row) * 1024 + k0 + c, lb + f * 8);
    }
    __syncthreads();
    bf16x8 af[4], bfr[4];
#pragma unroll
    for (int m = 0; m < 4; ++m)
      af[m] = *(const bf16x8*)(la + (wr * 64 + m * 16 + lrow) * 32 + lk);
#pragma unroll
    for (int n = 0; n < 4; ++n)
      bfr[n] = *(const bf16x8*)(lb + (wc * 64 + n * 16 + lrow) * 32 + lk);
#pragma unroll
    for (int m = 0; m < 4; ++m)
#pragma unroll
      for (int n = 0; n < 4; ++n)
        acc[m][n] = __builtin_amdgcn_mfma_f32_16x16x32_bf16(af[m], bfr[n],
                                                            acc[m][n], 0, 0, 0);
  }
}

// ---------------- fused QKV projection GEMM ----------------
// y=0: K (scale 1/32, (b,h,t,d)); y=1: Q (scale log2e/256, (b,h,t,d)); y=2: V (scale 1/32, (b,h,d,t))
__global__ __launch_bounds__(256) void qkv_gemm(
    const short* __restrict__ xb, const short* __restrict__ wk,
    const short* __restrict__ wq, const short* __restrict__ wv,
    unsigned short* __restrict__ kdst, unsigned short* __restrict__ qdst,
    unsigned short* __restrict__ vdst) {
  __shared__ short la[128 * 32];
  __shared__ short lb[128 * 32];
  __shared__ short vbuf[64 * 130];
  const int bid = blockIdx.x;
  const int swz = (bid & 7) * 64 + (bid >> 3);  // XCD-aware swizzle (512 = 8*64)
  const int mb = swz >> 3, nb = swz & 7;
  const short* Bm;
  unsigned short* dst;
  float scale;
  int vmode;
  if (blockIdx.y == 0)      { Bm = wk; dst = kdst; scale = 0.03125f;    vmode = 0; }
  else if (blockIdx.y == 1) { Bm = wq; dst = qdst; scale = 0.00390625f * 1.44269504088896340736f; vmode = 0; }
  else                      { Bm = wv; dst = vdst; scale = 0.03125f;    vmode = 1; }

  f32x4 acc[4][4];
  gemm_core(xb, Bm, mb * 128, nb * 128, la, lb, acc);

  const int tid = threadIdx.x;
  const int lane = tid & 63, wid = tid >> 6;
  const int wr = wid >> 1, wc = wid & 1;
  const int lg = lane >> 4, l15 = lane & 15;

  if (vmode == 0) {
#pragma unroll
    for (int m = 0; m < 4; ++m)
#pragma unroll
      for (int n = 0; n < 4; ++n)
#pragma unroll
        for (int r = 0; r < 4; ++r) {
          int gm = mb * 128 + wr * 64 + m * 16 + (lg << 2) + r;
          int gn = nb * 128 + wc * 64 + n * 16 + l15;
          int b = gm >> 11, t = gm & 2047;
          int h = gn >> 6, d = gn & 63;
          dst[(size_t)((b * NH + h) * T_SEQ + t) * HD + d] = f2bf(acc[m][n][r] * scale);
        }
  } else {
    // transpose through LDS -> coalesced Vt (b,h,d,t) writes
    const int b = mb >> 4;
    const int t0 = (mb & 15) * 128;
#pragma unroll
    for (int half = 0; half < 2; ++half) {
      __syncthreads();
      if (wc == half) {
#pragma unroll
        for (int m = 0; m < 4; ++m)
#pragma unroll
          for (int n = 0; n < 4; ++n)
#pragma unroll
            for (int rp = 0; rp < 2; ++rp) {
              int row = n * 16 + l15;                       // gn-local within half
              int col = wr * 64 + m * 16 + (lg << 2) + rp * 2;  // t-local
              *(unsigned int*)&vbuf[row * 130 + col] =
                  cvtpk(acc[m][n][rp * 2] * scale, acc[m][n][rp * 2 + 1] * scale);
            }
      }
      __syncthreads();
#pragma unroll
      for (int i = 0; i < 4; ++i) {
        int row = i * 16 + (tid >> 4);       // 0..63
        int col = (tid & 15) * 8;
        bf16x8 vv = *(const bf16x8*)&vbuf[row * 130 + col];
        int gn = nb * 128 + half * 64 + row;  // (h,d) flat 0..1023
        *(bf16x8*)(dst + ((size_t)b * 1024 + gn) * T_SEQ + t0 + col) = vv;
      }
    }
  }
}

// ---------------- flash attention v3 ----------------
// grid: 1024 blocks; block 256 = 4 waves. bh = bid&63, jb = bid>>6 (0..15).
// wave w handles q-chunk {jb, 31-jb, 32+jb, 63-jb}[w] (32 rows) -> per-block work constant.
// Q pre-scaled by C^-.5*hd^-.5*log2e; K,V by C^-.5. Vt is (b,h,d,t).
__global__ __launch_bounds__(256) void attn_kernel(
    const short* __restrict__ Q, const short* __restrict__ Km,
    const short* __restrict__ Vt, unsigned short* __restrict__ O) {
  __shared__ short olds[4][32 * 66];
  const int tid = threadIdx.x, lane = tid & 63, w = tid >> 6;
  const int bid = blockIdx.x;
  const int bh = bid & 63;
  const int jb = bid >> 6;
  const int qc = (w & 1) ? (((w >> 1) << 5) + 31 - jb) : (((w >> 1) << 5) + jb);
  const int q0w = qc * 32;
  const int hi = lane >> 5;
  const int l31 = lane & 31;

  const size_t base = (size_t)bh * T_SEQ * HD;
  const short* Qp = Q + base;
  const short* Kp = Km + base;
  const short* Vp = Vt + base;   // (d, t) rows of length 2048

  bf16x8 qf[4];
#pragma unroll
  for (int s = 0; s < 4; ++s)
    qf[s] = *(const bf16x8*)(Qp + (size_t)(q0w + l31) * HD + s * 16 + hi * 8);

  f32x16 oa, ob;
#pragma unroll
  for (int r = 0; r < 16; ++r) { oa[r] = 0.f; ob[r] = 0.f; }
  float m_r = -1e30f, l_r = 0.f;

  const int ntiles = (q0w + 95) >> 6;
  for (int it = 0; it < ntiles; ++it) {
    const int kb = it * 64;
    // ---- QK^T (S^T tiles: k rows x q cols) ----
    f32x16 s0, s1;
#pragma unroll
    for (int r = 0; r < 16; ++r) { s0[r] = 0.f; s1[r] = 0.f; }
    const short* Kb = Kp + (size_t)(kb + l31) * HD + hi * 8;
    bf16x8 kf0[4], kf1[4];
#pragma unroll
    for (int s = 0; s < 4; ++s) {
      kf0[s] = *(const bf16x8*)(Kb + s * 16);
      kf1[s] = *(const bf16x8*)(Kb + 32 * HD + s * 16);
    }
    __builtin_amdgcn_s_setprio(1);
#pragma unroll
    for (int s = 0; s < 4; ++s) {
      s0 = MFMA32(kf0[s], qf[s], s0);
      s1 = MFMA32(kf1[s], qf[s], s1);
    }
    __builtin_amdgcn_s_setprio(0);

    // ---- causal mask (boundary tiles only) ----
    if (kb + 63 > q0w) {
      const int q = q0w + l31;
#pragma unroll
      for (int r = 0; r < 16; ++r) {
        int k0 = kb + (r & 3) + 8 * (r >> 2) + 4 * hi;
        if (k0 > q) s0[r] = -1e30f;
        if (k0 + 32 > q) s1[r] = -1e30f;
      }
    }

    // ---- online softmax: tree max, defer-rescale (THR=8 in log2 domain) ----
    float tm[16];
#pragma unroll
    for (int r = 0; r < 16; ++r) tm[r] = fmaxf(s0[r], s1[r]);
#pragma unroll
    for (int r = 0; r < 8; ++r) tm[r] = fmaxf(tm[r], tm[r + 8]);
#pragma unroll
    for (int r = 0; r < 4; ++r) tm[r] = fmaxf(tm[r], tm[r + 4]);
    float mx = fmaxf(fmaxf(tm[0], tm[1]), fmaxf(tm[2], tm[3]));
    mx = fmaxf(mx, __shfl_xor(mx, 32));
    if (!__all(mx - m_r <= 8.0f)) {
      const float mn = fmaxf(m_r, mx);
      const float rsc = exp2f(m_r - mn);
      m_r = mn;
      l_r *= rsc;
#pragma unroll
      for (int r = 0; r < 16; ++r) { oa[r] *= rsc; ob[r] *= rsc; }
    }
    float ts[16];
#pragma unroll
    for (int r = 0; r < 16; ++r) {
      s0[r] = exp2f(s0[r] - m_r);
      s1[r] = exp2f(s1[r] - m_r);
      ts[r] = s0[r] + s1[r];
    }
#pragma unroll
    for (int r = 0; r < 8; ++r) ts[r] += ts[r + 8];
#pragma unroll
    for (int r = 0; r < 4; ++r) ts[r] += ts[r + 4];
    float rs = (ts[0] + ts[1]) + (ts[2] + ts[3]);
    rs += __shfl_xor(rs, 32);
    l_r += rs;

    // ---- pack P -> B-fragments (cvt_pk + shfl_xor(32) + select) ----
    bf16x8 pf[4];
    {
      unsigned int t0 = cvtpk(s0[0], s0[1]),  t1 = cvtpk(s0[2], s0[3]);
      unsigned int t2 = cvtpk(s0[4], s0[5]),  t3 = cvtpk(s0[6], s0[7]);
      unsigned int t4 = cvtpk(s0[8], s0[9]),  t5 = cvtpk(s0[10], s0[11]);
      unsigned int t6 = cvtpk(s0[12], s0[13]), t7 = cvtpk(s0[14], s0[15]);
      unsigned int o0 = __shfl_xor((int)t0, 32), o1 = __shfl_xor((int)t1, 32);
      unsigned int o2 = __shfl_xor((int)t2, 32), o3 = __shfl_xor((int)t3, 32);
      unsigned int o4 = __shfl_xor((int)t4, 32), o5 = __shfl_xor((int)t5, 32);
      unsigned int o6 = __shfl_xor((int)t6, 32), o7 = __shfl_xor((int)t7, 32);
      pf[0] = mk8(hi ? o2 : t0, hi ? o3 : t1, hi ? t2 : o0, hi ? t3 : o1);
      pf[1] = mk8(hi ? o6 : t4, hi ? o7 : t5, hi ? t6 : o4, hi ? t7 : o5);
    }
    {
      unsigned int t0 = cvtpk(s1[0], s1[1]),  t1 = cvtpk(s1[2], s1[3]);
      unsigned int t2 = cvtpk(s1[4], s1[5]),  t3 = cvtpk(s1[6], s1[7]);
      unsigned int t4 = cvtpk(s1[8], s1[9]),  t5 = cvtpk(s1[10], s1[11]);
      unsigned int t6 = cvtpk(s1[12], s1[13]), t7 = cvtpk(s1[14], s1[15]);
      unsigned int o0 = __shfl_xor((int)t0, 32), o1 = __shfl_xor((int)t1, 32);
      unsigned int o2 = __shfl_xor((int)t2, 32), o3 = __shfl_xor((int)t3, 32);
      unsigned int o4 = __shfl_xor((int)t4, 32), o5 = __shfl_xor((int)t5, 32);
      unsigned int o6 = __shfl_xor((int)t6, 32), o7 = __shfl_xor((int)t7, 32);
      pf[2] = mk8(hi ? o2 : t0, hi ? o3 : t1, hi ? t2 : o0, hi ? t3 : o1);
      pf[3] = mk8(hi ? o6 : t4, hi ? o7 : t5, hi ? t6 : o4, hi ? t7 : o5);
    }

    // ---- PV: O^T += V^T * P^T ----
    const short* Vb = Vp + (size_t)l31 * T_SEQ + kb + hi * 8;
    bf16x8 vf0[4], vf1[4];
#pragma unroll
    for (int ks = 0; ks < 4; ++ks) {
      vf0[ks] = *(const bf16x8*)(Vb + ks * 16);
      vf1[ks] = *(const bf16x8*)(Vb + 32 * T_SEQ + ks * 16);
    }
    __builtin_amdgcn_s_setprio(1);
#pragma unroll
    for (int ks = 0; ks < 4; ++ks) {
      oa = MFMA32(vf0[ks], pf[ks], oa);
      ob = MFMA32(vf1[ks], pf[ks], ob);
    }
    __builtin_amdgcn_s_setprio(0);
  }

  // ---- normalize + LDS transpose + coalesced O write (b, t, h*64+d) ----
  const float linv = 1.0f / l_r;
  const int b = bh >> 4, h = bh & 15;
  short* ol = &olds[w][0];
#pragma unroll
  for (int r = 0; r < 16; r += 2) {
    int d = (r & 3) + 8 * (r >> 2) + 4 * hi;
    *(unsigned int*)&ol[l31 * 66 + d]      = cvtpk(oa[r] * linv, oa[r + 1] * linv);
    *(unsigned int*)&ol[l31 * 66 + 32 + d] = cvtpk(ob[r] * linv, ob[r + 1] * linv);
  }
#pragma unroll
  for (int i = 0; i < 4; ++i) {
    int q = i * 8 + (lane >> 3);
    int c = (lane & 7) * 8;
    bf16x8 vv = *(const bf16x8*)&ol[q * 66 + c];
    *(bf16x8*)(O + (size_t)(b * T_SEQ + q0w + q) * 1024 + h * 64 + c) = vv;
  }
}

// ---------------- output projection GEMM (writes f32) ----------------
__global__ __launch_bounds__(256) void proj_gemm(const short* __restrict__ ain,
                                                 const short* __restrict__ wp,
                                                 float* __restrict__ out) {
  __shared__ short la[128 * 32];
  __shared__ short lb[128 * 32];
  const int bid = blockIdx.x;
  const int swz = (bid & 7) * 64 + (bid >> 3);
  const int mb = swz >> 3, nb = swz & 7;
  f32x4 acc[4][4];
  gemm_core(ain, wp, mb * 128, nb * 128, la, lb, acc);
  const int lane = threadIdx.x & 63, wid = threadIdx.x >> 6;
  const int wr = wid >> 1, wc = wid & 1;
#pragma unroll
  for (int m = 0; m < 4; ++m)
#pragma unroll
    for (int n = 0; n < 4; ++n)
#pragma unroll
      for (int r = 0; r < 4; ++r) {
        int gm = mb * 128 + wr * 64 + m * 16 + ((lane >> 4) << 2) + r;
        int gn = nb * 128 + wc * 64 + n * 16 + (lane & 15);
        out[(size_t)gm * 1024 + gn] = acc[m][n][r] * 0.03125f;
      }
}

extern "C" void kernel_launch(void* const* d_in, const int* in_sizes, int n_in,
                              void* d_out, int out_size, void* d_ws, size_t ws_size,
                              hipStream_t stream) {
  const float* x  = (const float*)d_in[0];
  const float* Wk = (const float*)d_in[1];
  const float* Wq = (const float*)d_in[2];
  const float* Wv = (const float*)d_in[3];
  const float* Wp = (const float*)d_in[4];
  float* out = (float*)d_out;
  char* ws = (char*)d_ws;
  const size_t MB = 1024ull * 1024ull;

  unsigned short* q_ws = (unsigned short*)(ws + 0 * MB);
  unsigned short* k_ws = (unsigned short*)(ws + 16 * MB);
  unsigned short* v_ws = (unsigned short*)(ws + 32 * MB);   // transposed (b,h,d,t)
  unsigned short* xa   = (unsigned short*)(ws + 48 * MB);   // x bf16, later attn-out
  unsigned short* wkb  = (unsigned short*)(ws + 64 * MB);
  unsigned short* wqb  = wkb + 1048576;
  unsigned short* wvb  = wqb + 1048576;
  unsigned short* wpb  = wvb + 1048576;

  cvt_f32_bf16<<<8192, 256, 0, stream>>>(x, xa, 2097152);
  cvt4_w<<<4096, 256, 0, stream>>>(Wk, Wq, Wv, Wp, wkb, wqb, wvb, wpb);

  qkv_gemm<<<dim3(512, 3), 256, 0, stream>>>(
      (const short*)xa, (const short*)wkb, (const short*)wqb, (const short*)wvb,
      k_ws, q_ws, v_ws);

  attn_kernel<<<1024, 256, 0, stream>>>(
      (const short*)q_ws, (const short*)k_ws, (const short*)v_ws, xa);

  proj_gemm<<<512, 256, 0, stream>>>((const short*)xa, (const short*)wpb, out);
}